// Round 10
// baseline (330.304 us; speedup 1.0000x reference)
//
#include <hip/hip_runtime.h>

typedef unsigned short ushort_t;
typedef __attribute__((ext_vector_type(8))) __bf16 bf16x8;
typedef __attribute__((ext_vector_type(4))) __bf16 bf16x4;
typedef __attribute__((ext_vector_type(4))) float f32x4;

__device__ inline float bf2f(ushort_t u) {
  union { unsigned int i; float f; } v; v.i = ((unsigned int)u) << 16; return v.f;
}
__device__ inline ushort_t f2bf(float f) {
  union { float f; unsigned int i; } v; v.f = f;
  unsigned int r = (v.i + 0x7fffu + ((v.i >> 16) & 1u)) >> 16;
  return (ushort_t)r;
}

// ---------------------------------------------------------------------------
// Dtype self-detection (flag=1: bf16 inputs, 0: fp32 inputs). Wave-parallel.
// ---------------------------------------------------------------------------
__global__ void detect_dtype_kernel(const ushort_t* __restrict__ w,
                                    int* __restrict__ flag) {
  int lane = threadIdx.x & 63;
  int cnt = 0;
  for (int i = 0; i < 4; i++) {
    float a = fabsf(bf2f(w[lane * 4 + i]));
    if (a >= 1e-4f && a <= 0.5f) cnt++;
  }
  for (int off = 1; off < 64; off <<= 1) cnt += __shfl_xor(cnt, off, 64);
  if (threadIdx.x == 0) *flag = (cnt >= 192) ? 1 : 0;
}

__device__ inline float ld1(const void* src, size_t idx, int isbf) {
  return isbf ? bf2f(((const ushort_t*)src)[idx]) : ((const float*)src)[idx];
}

// Register prefetch container (R5 lesson: named values only, never arrays
// passed by pointer — those go to scratch = HBM writes).
struct pre8 { float4 a, b; };
__device__ inline pre8 pref8(const void* src, size_t idx, int isbf) {
  pre8 u;
  if (isbf) {
    u.a = *(const float4*)((const ushort_t*)src + idx);
    u.b = u.a;
  } else {
    const float* s = (const float*)src + idx;
    u.a = *(const float4*)s;
    u.b = *(const float4*)(s + 4);
  }
  return u;
}
__device__ inline void commit8(ushort_t* dst, pre8 u, int isbf) {
  if (isbf) {
    *(float4*)dst = u.a;
  } else {
    union { bf16x8 v; ushort_t u8[8]; } t;
    t.u8[0] = f2bf(u.a.x); t.u8[1] = f2bf(u.a.y); t.u8[2] = f2bf(u.a.z); t.u8[3] = f2bf(u.a.w);
    t.u8[4] = f2bf(u.b.x); t.u8[5] = f2bf(u.b.y); t.u8[6] = f2bf(u.b.z); t.u8[7] = f2bf(u.b.w);
    *(bf16x8*)dst = t.v;
  }
}
__device__ inline void cvt8(ushort_t* dst, const void* src, size_t idx, int isbf) {
  commit8(dst, pref8(src, idx, isbf), isbf);
}

// ---------------------------------------------------------------------------
// PREP: bf16 conversion of W (segs 0-3) + X (segs 4-6), and mask transpose
// Mt[b][k][q] (seg 7) — merged into one launch. Coalesced b128 on both
// global sides of the transpose (R3 lesson: never 2B line-stride HBM stores).
// ---------------------------------------------------------------------------
#define NW_ ((size_t)1024 * 1024)
#define NX_ ((size_t)4096 * 1024)
#define NM_ ((size_t)2 * 2048 * 2048)

__global__ __launch_bounds__(256) void prep_kernel(
    const void* xq, const void* xk, const void* xv,
    const void* wq, const void* wk, const void* wv, const void* wo,
    const void* mask, ushort_t* __restrict__ dst, ushort_t* __restrict__ Mt,
    const int* __restrict__ flag) {
  __shared__ ushort_t T[64][72];
  const int seg = blockIdx.z;
  const int f = *flag;
  if (seg < 7) {
    const void* src; size_t n, doff;
    switch (seg) {
      case 0: src = wq; n = NW_; doff = 0;                 break;
      case 1: src = wk; n = NW_; doff = NW_;               break;
      case 2: src = wv; n = NW_; doff = 2 * NW_;           break;
      case 3: src = wo; n = NW_; doff = 3 * NW_;           break;
      case 4: src = xq; n = NX_; doff = 4 * NW_;           break;
      case 5: src = xk; n = NX_; doff = 4 * NW_ + NX_;     break;
      default: src = xv; n = NX_; doff = 4 * NW_ + 2 * NX_; break;
    }
    size_t i = ((size_t)blockIdx.x * 256 + threadIdx.x) * 8;
    if (i >= n) return;
    cvt8(&dst[doff + i], src, i, f);
  } else {
    // mask transpose: x in [0,2048): b = x>>10; q0/k0 64-tiles
    const int x = blockIdx.x;
    const int b = x >> 10, rem = x & 1023;
    const int q0 = (rem & 31) * 64, k0 = (rem >> 5) * 64;
    const int tid = threadIdx.x;
    const int r = tid >> 2, c = (tid & 3) * 16;
    const size_t src = (size_t)b * 2048 * 2048 + (size_t)(q0 + r) * 2048 + k0 + c;
    cvt8(&T[r][c],     mask, src, f);
    cvt8(&T[r][c + 8], mask, src + 8, f);
    __syncthreads();
    union { bf16x8 v; ushort_t u[8]; } o0, o1;
    for (int i = 0; i < 8; i++) o0.u[i] = T[c + i][r];
    for (int i = 0; i < 8; i++) o1.u[i] = T[c + 8 + i][r];
    ushort_t* d = Mt + (size_t)b * 2048 * 2048;
    *(bf16x8*)&d[(size_t)(k0 + r) * 2048 + q0 + c]     = o0.v;
    *(bf16x8*)&d[(size_t)(k0 + r) * 2048 + q0 + c + 8] = o1.v;
  }
}

// ---------------------------------------------------------------------------
// FAST GEMM (m97-style, validated R7): bf16 operands, global_load_lds,
// XOR-swizzled LDS. M-tile 128, N-tile NT (128 or 64), BK=64.
// NT=64 doubles block count for latency-exposed shapes (out_proj: 1->2
// blocks/CU). (R3 lesson: epilogue MODE compile-time.)
// ---------------------------------------------------------------------------
#define KDIM 1024
#define NDIM 1024

__device__ __forceinline__ void gld_lds16(ushort_t* lds, const ushort_t* g) {
  __builtin_amdgcn_global_load_lds(
      (const __attribute__((address_space(1))) void*)g,
      (__attribute__((address_space(3))) void*)lds, 16, 0, 0);
}

template <int MODE, int NT>
__global__ __launch_bounds__(256) void gemm_fast_kernel(
    const ushort_t* __restrict__ X0, const ushort_t* __restrict__ X1,
    const ushort_t* __restrict__ X2,
    const ushort_t* __restrict__ W0, const ushort_t* __restrict__ W1,
    const ushort_t* __restrict__ W2,
    const void* __restrict__ B0, const void* __restrict__ B1,
    const void* __restrict__ B2,
    void* __restrict__ O0, void* __restrict__ O1, void* __restrict__ O2,
    const int* __restrict__ flag) {
  constexpr int NJ = NT / 32;           // j-frags per wave (4 or 2)
  __shared__ ushort_t As[128 * 64];
  __shared__ ushort_t Bs[NT * 64];
  const int z = blockIdx.z;
  const ushort_t* X = z == 0 ? X0 : z == 1 ? X1 : X2;
  const ushort_t* W = z == 0 ? W0 : z == 1 ? W1 : W2;
  const void* Bias  = z == 0 ? B0 : z == 1 ? B1 : B2;
  void* Out         = z == 0 ? O0 : z == 1 ? O1 : O2;
  const int f = *flag;

  const int tid = threadIdx.x;
  const int wave = tid >> 6, lane = tid & 63;
  const int g = lane >> 4, l16 = lane & 15;
  const int m0 = blockIdx.y * 128, n0 = blockIdx.x * NT;
  const int wm = (wave >> 1) * 64, wn = (wave & 1) * (NT / 2);
  const int lr = lane >> 3;
  const int lc = (lane & 7) ^ lr;

  f32x4 acc[4][NJ] = {};

  for (int k0 = 0; k0 < KDIM; k0 += 64) {
#pragma unroll
    for (int q = 0; q < 4; q++) {
      const int row = wave * 32 + q * 8;
      gld_lds16(&As[row * 64], &X[(size_t)(m0 + row + lr) * KDIM + k0 + lc * 8]);
    }
#pragma unroll
    for (int q = 0; q < NT / 32; q++) {
      const int row = wave * (NT / 4) + q * 8;
      gld_lds16(&Bs[row * 64], &W[(size_t)(n0 + row + lr) * KDIM + k0 + lc * 8]);
    }
    __syncthreads();

    bf16x8 af[2][4], bfr[2][NJ];
#pragma unroll
    for (int kk = 0; kk < 2; kk++) {
      const int cs = ((g + 4 * kk) ^ (l16 & 7)) * 8;
#pragma unroll
      for (int i = 0; i < 4; i++)
        af[kk][i]  = *(const bf16x8*)&As[(wm + i * 16 + l16) * 64 + cs];
#pragma unroll
      for (int j = 0; j < NJ; j++)
        bfr[kk][j] = *(const bf16x8*)&Bs[(wn + j * 16 + l16) * 64 + cs];
    }
#pragma unroll
    for (int kk = 0; kk < 2; kk++)
#pragma unroll
      for (int i = 0; i < 4; i++)
#pragma unroll
        for (int j = 0; j < NJ; j++)
          acc[i][j] = __builtin_amdgcn_mfma_f32_16x16x32_bf16(
              af[kk][i], bfr[kk][j], acc[i][j], 0, 0, 0);
    __syncthreads();
  }

  for (int i = 0; i < 4; i++)
    for (int j = 0; j < NJ; j++)
      for (int r = 0; r < 4; r++) {
        int m = m0 + wm + i * 16 + g * 4 + r;   // C/D: row=(lane>>4)*4+reg
        int n = n0 + wn + j * 16 + l16;         //      col=lane&15
        float v = acc[i][j][r] + ld1(Bias, n, f);
        if (MODE == 0) {
          if (f) ((ushort_t*)Out)[(size_t)m * NDIM + n] = f2bf(v);
          else   ((float*)Out)[(size_t)m * NDIM + n] = v;
        } else {
          int b = m >> 11, s = m & 2047, h = n >> 6, d = n & 63;
          ((ushort_t*)Out)[((((size_t)b * 16 + h) * 2048) + s) * 64 + d] = f2bf(v);
        }
      }
}

// ---------------------------------------------------------------------------
// FALLBACK GEMM (any dtype): VGPR-roundtrip staging, BK=32.
// ---------------------------------------------------------------------------
#define BK 32

template <int MODE>
__device__ inline void gemm_body(const void* __restrict__ X,
                                 const void* __restrict__ W,
                                 const void* __restrict__ Bias,
                                 void* __restrict__ Out,
                                 int xbf, int wbf, int bbf, int obf) {
  __shared__ ushort_t As[128][BK + 8];
  __shared__ ushort_t Bs[128][BK + 8];
  const int tid = threadIdx.x;
  const int wave = tid >> 6, lane = tid & 63;
  const int g = lane >> 4, l16 = lane & 15;
  const int m0 = blockIdx.y * 128, n0 = blockIdx.x * 128;
  const int wm = (wave >> 1) * 64, wn = (wave & 1) * 64;

  f32x4 acc[4][4] = {};
  const int r0 = tid >> 2, c0 = (tid & 3) * 8;
  const size_t ia0 = (size_t)(m0 + r0) * KDIM + c0;
  const size_t ia1 = (size_t)(m0 + r0 + 64) * KDIM + c0;
  const size_t ib0 = (size_t)(n0 + r0) * KDIM + c0;
  const size_t ib1 = (size_t)(n0 + r0 + 64) * KDIM + c0;

  pre8 pa0 = pref8(X, ia0, xbf), pa1 = pref8(X, ia1, xbf);
  pre8 pb0 = pref8(W, ib0, wbf), pb1 = pref8(W, ib1, wbf);

  for (int k0 = 0; k0 < KDIM; k0 += BK) {
    commit8(&As[r0][c0],      pa0, xbf);
    commit8(&As[r0 + 64][c0], pa1, xbf);
    commit8(&Bs[r0][c0],      pb0, wbf);
    commit8(&Bs[r0 + 64][c0], pb1, wbf);
    const int kn = (k0 + BK) & (KDIM - 1);
    pa0 = pref8(X, ia0 + kn, xbf); pa1 = pref8(X, ia1 + kn, xbf);
    pb0 = pref8(W, ib0 + kn, wbf); pb1 = pref8(W, ib1 + kn, wbf);
    __syncthreads();
    bf16x8 af[4], bfr[4];
    for (int i = 0; i < 4; i++) af[i]  = *(const bf16x8*)&As[wm + i * 16 + l16][g * 8];
    for (int j = 0; j < 4; j++) bfr[j] = *(const bf16x8*)&Bs[wn + j * 16 + l16][g * 8];
    for (int i = 0; i < 4; i++)
      for (int j = 0; j < 4; j++)
        acc[i][j] = __builtin_amdgcn_mfma_f32_16x16x32_bf16(af[i], bfr[j], acc[i][j], 0, 0, 0);
    __syncthreads();
  }
  for (int i = 0; i < 4; i++)
    for (int j = 0; j < 4; j++)
      for (int r = 0; r < 4; r++) {
        int m = m0 + wm + i * 16 + g * 4 + r;
        int n = n0 + wn + j * 16 + l16;
        float v = acc[i][j][r] + ld1(Bias, n, bbf);
        if (MODE == 0) {
          if (obf) ((ushort_t*)Out)[(size_t)m * NDIM + n] = f2bf(v);
          else     ((float*)Out)[(size_t)m * NDIM + n] = v;
        } else {
          int b = m >> 11, s = m & 2047, h = n >> 6, d = n & 63;
          ((ushort_t*)Out)[((((size_t)b * 16 + h) * 2048) + s) * 64 + d] = f2bf(v);
        }
      }
}

__global__ __launch_bounds__(256) void proj_qkv_fb_kernel(
    const void* __restrict__ query, const void* __restrict__ key,
    const void* __restrict__ value,
    const void* __restrict__ Wq, const void* __restrict__ bq,
    const void* __restrict__ Wk, const void* __restrict__ bk,
    const void* __restrict__ Wv, const void* __restrict__ bv,
    ushort_t* __restrict__ Q, ushort_t* __restrict__ K, ushort_t* __restrict__ V,
    const int* __restrict__ flag) {
  int f = *flag;
  int z = blockIdx.z;
  const void* X = z == 0 ? query : z == 1 ? key : value;
  const void* W = z == 0 ? Wq : z == 1 ? Wk : Wv;
  const void* B = z == 0 ? bq : z == 1 ? bk : bv;
  ushort_t* O  = z == 0 ? Q  : z == 1 ? K  : V;
  gemm_body<1>(X, W, B, O, f, f, f, 1);
}

__global__ __launch_bounds__(256) void out_proj_fb_kernel(
    const ushort_t* __restrict__ X, const void* __restrict__ W,
    const void* __restrict__ B, void* __restrict__ O,
    const int* __restrict__ flag) {
  int f = *flag;
  gemm_body<0>(X, W, B, O, 1, f, f, f);
}

// ---------------------------------------------------------------------------
// V transpose: Vt[bh][d][s] = V[bh][s][d]. Validated R5.
// ---------------------------------------------------------------------------
__global__ __launch_bounds__(256) void transpose_v_kernel(
    const ushort_t* __restrict__ Vin, ushort_t* __restrict__ Vout) {
  __shared__ ushort_t T[64][72];
  const int tid = threadIdx.x;
  const int r = tid >> 2, c = (tid & 3) * 16;
  const int bh = blockIdx.y;
  const int s0 = blockIdx.x * 64;
  const ushort_t* src = Vin + (size_t)bh * 2048 * 64;
  *(bf16x8*)&T[r][c]     = *(const bf16x8*)&src[(size_t)(s0 + r) * 64 + c];
  *(bf16x8*)&T[r][c + 8] = *(const bf16x8*)&src[(size_t)(s0 + r) * 64 + c + 8];
  __syncthreads();
  union { bf16x8 v; ushort_t u[8]; } o0, o1;
  for (int i = 0; i < 8; i++) o0.u[i] = T[c + i][r];
  for (int i = 0; i < 8; i++) o1.u[i] = T[c + 8 + i][r];
  ushort_t* dst = Vout + (size_t)bh * 64 * 2048;
  *(bf16x8*)&dst[(size_t)r * 2048 + s0 + c]     = o0.v;
  *(bf16x8*)&dst[(size_t)r * 2048 + s0 + c + 8] = o1.v;
}

// ---------------------------------------------------------------------------
// Flash attention v8 (q-tile 128, optional K-split). SPLIT=1: z in {0,1}
// processes K half [z*1024, z*1024+1024), writes unnormalized fp32 O
// partials (at Opart + z*E) + l sums (exact merge: no online max, so
// halves combine as (o1+o2)/(l1+l2)). 1024 blocks -> 3 blocks/CU (LDS
// 53760x3 <= 163840). SPLIT=0: full K, writes ctx directly (R8-validated).
// Mask from pre-transposed bf16 Mt[b][k][q] (ds_read_b64 of 4 contiguous q).
// R9 BUG (fixed in R10): launcher passed Opart+2E (==Lpart) as O1 to the
// combine; partials live at Opart+0 and Opart+E.
// ---------------------------------------------------------------------------
template <int SPLIT>
__global__ __launch_bounds__(256, 2) void flash_attn128_kernel(
    const ushort_t* __restrict__ Q, const ushort_t* __restrict__ K,
    const ushort_t* __restrict__ Vt, const ushort_t* __restrict__ Mt,
    ushort_t* __restrict__ ctx, float* __restrict__ Opart,
    float* __restrict__ Lpart) {
  __shared__ ushort_t Ks[64 * 72];
  __shared__ ushort_t Vs[64 * 72];
  __shared__ ushort_t MQ[8448];        // Q staging 128x66, then mask 64x132
  __shared__ ushort_t Ps[4][32 * 72];  // per-wave P tile [32q][64k]

  const int tid = threadIdx.x;
  const int wave = tid >> 6, lane = tid & 63;
  const int g = lane >> 4, l16 = lane & 15;
  const int bh = blockIdx.x;
  const int b = bh >> 4, h = bh & 15;
  const int q0 = blockIdx.y * 128;
  const int z = SPLIT ? blockIdx.z : 0;
  const int kbase = z * 1024, kend = SPLIT ? kbase + 1024 : 2048;

  const ushort_t* Qh = Q + (size_t)bh * 2048 * 64;
  const ushort_t* Kh = K + (size_t)bh * 2048 * 64;
  const ushort_t* Vh = Vt + (size_t)bh * 64 * 2048;            // [d][s]
  const ushort_t* Mh = Mt + (size_t)b * 2048 * 2048 + q0;      // [k][q0..]

  // ---- Q stage (128x64 into MQ stride 66) with exact 1/8 prescale ----
  {
    const int qr = tid >> 1, qc = (tid & 1) * 32;
#pragma unroll
    for (int ch = 0; ch < 4; ch++) {
      union { bf16x8 v; ushort_t u[8]; } a;
      a.v = *(const bf16x8*)&Qh[(size_t)(q0 + qr) * 64 + qc + ch * 8];
      for (int i = 0; i < 8; i++) a.u[i] = f2bf(bf2f(a.u[i]) * 0.125f);
      *(bf16x8*)&MQ[qr * 66 + qc + ch * 8] = a.v;
    }
  }
  __syncthreads();
  bf16x8 aq[2][2];
#pragma unroll
  for (int t = 0; t < 2; t++)
#pragma unroll
    for (int kk = 0; kk < 2; kk++)
      aq[t][kk] = *(const bf16x8*)&MQ[(wave * 32 + t * 16 + l16) * 66 + kk * 32 + g * 8];
  // iter-0 barrier A orders these reads before any wave's mask writes to MQ.

  float lpart[2][4] = {};
  f32x4 o_acc[2][4] = {};

  const int r = tid >> 2, c = (tid & 3) * 16;     // K/V staging coords
  const int mc = (tid & 3) * 32;                  // mask staging col base

  // ---- prologue prefetch (named regs only — R5 lesson) ----
  bf16x8 kr0 = *(const bf16x8*)&Kh[(size_t)(kbase + r) * 64 + c];
  bf16x8 kr1 = *(const bf16x8*)&Kh[(size_t)(kbase + r) * 64 + c + 8];
  bf16x8 vr0 = *(const bf16x8*)&Vh[(size_t)r * 2048 + kbase + c];
  bf16x8 vr1 = *(const bf16x8*)&Vh[(size_t)r * 2048 + kbase + c + 8];
  bf16x8 pm0 = *(const bf16x8*)&Mh[(size_t)(kbase + r) * 2048 + mc];
  bf16x8 pm1 = *(const bf16x8*)&Mh[(size_t)(kbase + r) * 2048 + mc + 8];
  bf16x8 pm2 = *(const bf16x8*)&Mh[(size_t)(kbase + r) * 2048 + mc + 16];
  bf16x8 pm3 = *(const bf16x8*)&Mh[(size_t)(kbase + r) * 2048 + mc + 24];

  for (int kt0 = kbase; kt0 < kend; kt0 += 64) {
    __syncthreads();   // A: all waves done with prev Ks/Vs/MQ/Ps reads
    *(bf16x8*)&Ks[r * 72 + c]      = kr0;
    *(bf16x8*)&Ks[r * 72 + c + 8]  = kr1;
    *(bf16x8*)&Vs[r * 72 + c]      = vr0;
    *(bf16x8*)&Vs[r * 72 + c + 8]  = vr1;
    *(bf16x8*)&MQ[r * 132 + mc]      = pm0;
    *(bf16x8*)&MQ[r * 132 + mc + 8]  = pm1;
    *(bf16x8*)&MQ[r * 132 + mc + 16] = pm2;
    *(bf16x8*)&MQ[r * 132 + mc + 24] = pm3;
    __syncthreads();   // B: staging visible

    // ---- issue next-tile loads; drained at next barrier A ----
    const int ktn = (kt0 + 64) & 2047;            // wrap: last pref harmless
    kr0 = *(const bf16x8*)&Kh[(size_t)(ktn + r) * 64 + c];
    kr1 = *(const bf16x8*)&Kh[(size_t)(ktn + r) * 64 + c + 8];
    vr0 = *(const bf16x8*)&Vh[(size_t)r * 2048 + ktn + c];
    vr1 = *(const bf16x8*)&Vh[(size_t)r * 2048 + ktn + c + 8];
    pm0 = *(const bf16x8*)&Mh[(size_t)(ktn + r) * 2048 + mc];
    pm1 = *(const bf16x8*)&Mh[(size_t)(ktn + r) * 2048 + mc + 8];
    pm2 = *(const bf16x8*)&Mh[(size_t)(ktn + r) * 2048 + mc + 16];
    pm3 = *(const bf16x8*)&Mh[(size_t)(ktn + r) * 2048 + mc + 24];

    // ---- scores: 32 q-rows x 64 k-cols per wave ----
    f32x4 sc[2][4] = {};
#pragma unroll
    for (int j = 0; j < 4; j++) {
      bf16x8 bk0 = *(const bf16x8*)&Ks[(j * 16 + l16) * 72 + g * 8];
      bf16x8 bk1 = *(const bf16x8*)&Ks[(j * 16 + l16) * 72 + 32 + g * 8];
#pragma unroll
      for (int t = 0; t < 2; t++) {
        sc[t][j] = __builtin_amdgcn_mfma_f32_16x16x32_bf16(aq[t][0], bk0, sc[t][j], 0, 0, 0);
        sc[t][j] = __builtin_amdgcn_mfma_f32_16x16x32_bf16(aq[t][1], bk1, sc[t][j], 0, 0, 0);
      }
    }

    // ---- p = exp(s*m); mask via ds_read_b64 (4 contiguous q); bf16 P ----
#pragma unroll
    for (int t = 0; t < 2; t++)
#pragma unroll
      for (int j = 0; j < 4; j++) {
        union { bf16x4 v; ushort_t u[4]; } m4;
        m4.v = *(const bf16x4*)&MQ[(j * 16 + l16) * 132 + wave * 32 + t * 16 + g * 4];
#pragma unroll
        for (int rr = 0; rr < 4; rr++) {
          float s = fminf(sc[t][j][rr] * bf2f(m4.u[rr]), 80.f);
          float p = __expf(s);
          unsigned int pb = __float_as_uint(p);
          lpart[t][rr] += __uint_as_float(pb & 0xffff0000u);
          Ps[wave][(t * 16 + g * 4 + rr) * 72 + j * 16 + l16] = (ushort_t)(pb >> 16);
        }
      }
    asm volatile("" ::: "memory");   // keep ds_reads below after ds_writes

    // ---- PV: o_acc[t][jd] += P[t] x V ----
    bf16x8 pf00 = *(const bf16x8*)&Ps[wave][(l16) * 72 + g * 8];
    bf16x8 pf01 = *(const bf16x8*)&Ps[wave][(l16) * 72 + 32 + g * 8];
    bf16x8 pf10 = *(const bf16x8*)&Ps[wave][(16 + l16) * 72 + g * 8];
    bf16x8 pf11 = *(const bf16x8*)&Ps[wave][(16 + l16) * 72 + 32 + g * 8];
#pragma unroll
    for (int jd = 0; jd < 4; jd++) {
      bf16x8 vf0 = *(const bf16x8*)&Vs[(jd * 16 + l16) * 72 + g * 8];
      bf16x8 vf1 = *(const bf16x8*)&Vs[(jd * 16 + l16) * 72 + 32 + g * 8];
      o_acc[0][jd] = __builtin_amdgcn_mfma_f32_16x16x32_bf16(pf00, vf0, o_acc[0][jd], 0, 0, 0);
      o_acc[0][jd] = __builtin_amdgcn_mfma_f32_16x16x32_bf16(pf01, vf1, o_acc[0][jd], 0, 0, 0);
      o_acc[1][jd] = __builtin_amdgcn_mfma_f32_16x16x32_bf16(pf10, vf0, o_acc[1][jd], 0, 0, 0);
      o_acc[1][jd] = __builtin_amdgcn_mfma_f32_16x16x32_bf16(pf11, vf1, o_acc[1][jd], 0, 0, 0);
    }
  }

  // ---- epilogue ----
  if (SPLIT) {
    float* Ow = Opart + (size_t)z * ((size_t)2 * 2048 * 1024);
    float* Lw = Lpart + (size_t)z * (32 * 2048);
#pragma unroll
    for (int t = 0; t < 2; t++) {
      float ls[4];
#pragma unroll
      for (int rr = 0; rr < 4; rr++) {
        float l = lpart[t][rr];
        l += __shfl_xor(l, 1, 64);
        l += __shfl_xor(l, 2, 64);
        l += __shfl_xor(l, 4, 64);
        l += __shfl_xor(l, 8, 64);
        ls[rr] = l;
      }
      if (l16 == 0)
#pragma unroll
        for (int rr = 0; rr < 4; rr++)
          Lw[(size_t)bh * 2048 + q0 + wave * 32 + t * 16 + g * 4 + rr] = ls[rr];
#pragma unroll
      for (int jd = 0; jd < 4; jd++)
#pragma unroll
        for (int rr = 0; rr < 4; rr++) {
          int qrow = q0 + wave * 32 + t * 16 + g * 4 + rr;
          Ow[((size_t)b * 2048 + qrow) * 1024 + h * 64 + jd * 16 + l16] =
              o_acc[t][jd][rr];
        }
    }
  } else {
#pragma unroll
    for (int t = 0; t < 2; t++) {
      float rl[4];
#pragma unroll
      for (int rr = 0; rr < 4; rr++) {
        float l = lpart[t][rr];
        l += __shfl_xor(l, 1, 64);
        l += __shfl_xor(l, 2, 64);
        l += __shfl_xor(l, 4, 64);
        l += __shfl_xor(l, 8, 64);
        rl[rr] = 1.0f / l;
      }
#pragma unroll
      for (int jd = 0; jd < 4; jd++)
#pragma unroll
        for (int rr = 0; rr < 4; rr++) {
          int qrow = q0 + wave * 32 + t * 16 + g * 4 + rr;
          ctx[((size_t)b * 2048 + qrow) * 1024 + h * 64 + jd * 16 + l16] =
              f2bf(o_acc[t][jd][rr] * rl[rr]);
        }
    }
  }
}

// ---------------------------------------------------------------------------
// Combine: ctx = (O0 + O1) / (L0 + L1). Exact merge of the two K-halves.
// ---------------------------------------------------------------------------
__global__ __launch_bounds__(256) void combine_kernel(
    const float* __restrict__ O0, const float* __restrict__ O1,
    const float* __restrict__ L0, const float* __restrict__ L1,
    ushort_t* __restrict__ ctx) {
  size_t i = ((size_t)blockIdx.x * 256 + threadIdx.x) * 4;
  int h = (int)((i & 1023) >> 6);
  size_t s = (i >> 10) & 2047, b = i >> 21;
  size_t li = (b * 16 + h) * 2048 + s;
  float rl = 1.0f / (L0[li] + L1[li]);
  float4 a = *(const float4*)&O0[i];
  float4 c = *(const float4*)&O1[i];
  union { bf16x4 v; ushort_t u[4]; } o;
  o.u[0] = f2bf((a.x + c.x) * rl);
  o.u[1] = f2bf((a.y + c.y) * rl);
  o.u[2] = f2bf((a.z + c.z) * rl);
  o.u[3] = f2bf((a.w + c.w) * rl);
  *(bf16x4*)&ctx[i] = o.v;
}

// ---------------------------------------------------------------------------
// Fallback flash (R7, validated): q-tile 64, mask from global (any dtype).
// ---------------------------------------------------------------------------
#define FS 72

template <int PRET>
__global__ __launch_bounds__(256, 4) void flash_attn_kernel(
    const ushort_t* __restrict__ Q, const ushort_t* __restrict__ K,
    const ushort_t* __restrict__ V, const void* __restrict__ mask,
    ushort_t* __restrict__ ctx, const int* __restrict__ flag) {
  __shared__ ushort_t QsM[64][FS];
  __shared__ ushort_t Ks[64][FS];
  __shared__ ushort_t Vs[64][FS];
  __shared__ ushort_t Ps[4][16][FS];

  const int mbf = *flag;
  const int tid = threadIdx.x;
  const int wave = tid >> 6, lane = tid & 63;
  const int g = lane >> 4, l16 = lane & 15;
  const int bh = blockIdx.x;
  const int b = bh >> 4, h = bh & 15;
  const int q0 = blockIdx.y * 64;

  const ushort_t* Qh = Q + (size_t)bh * 2048 * 64;
  const ushort_t* Kh = K + (size_t)bh * 2048 * 64;
  const ushort_t* Vh = PRET ? V + (size_t)bh * 64 * 2048
                            : V + (size_t)bh * 2048 * 64;
  const int mrow = wave * 16 + g * 4;
  const int r = tid >> 2, c = (tid & 3) * 16;
  const size_t mstage = (size_t)b * 2048 * 2048 + (size_t)(q0 + r) * 2048 + c;

  {
    union { bf16x8 v; ushort_t u[8]; } a0, a1;
    a0.v = *(const bf16x8*)&Qh[(size_t)(q0 + r) * 64 + c];
    a1.v = *(const bf16x8*)&Qh[(size_t)(q0 + r) * 64 + c + 8];
    for (int i = 0; i < 8; i++) {
      a0.u[i] = f2bf(bf2f(a0.u[i]) * 0.125f);
      a1.u[i] = f2bf(bf2f(a1.u[i]) * 0.125f);
    }
    *(bf16x8*)&QsM[r][c]     = a0.v;
    *(bf16x8*)&QsM[r][c + 8] = a1.v;
  }
  __syncthreads();
  const bf16x8 aq0 = *(const bf16x8*)&QsM[wave * 16 + l16][g * 8];
  const bf16x8 aq1 = *(const bf16x8*)&QsM[wave * 16 + l16][32 + g * 8];

  float lpart[4] = {0.f, 0.f, 0.f, 0.f};
  f32x4 o_acc[4] = {};

  bf16x8 kr0 = *(const bf16x8*)&Kh[(size_t)r * 64 + c];
  bf16x8 kr1 = *(const bf16x8*)&Kh[(size_t)r * 64 + c + 8];
  bf16x8 vr0, vr1;
  if (PRET) {
    vr0 = *(const bf16x8*)&Vh[(size_t)r * 2048 + c];
    vr1 = *(const bf16x8*)&Vh[(size_t)r * 2048 + c + 8];
  } else {
    vr0 = *(const bf16x8*)&Vh[(size_t)r * 64 + c];
    vr1 = *(const bf16x8*)&Vh[(size_t)r * 64 + c + 8];
  }
  pre8 pm0 = pref8(mask, mstage, mbf);
  pre8 pm1 = pref8(mask, mstage + 8, mbf);

  for (int kt0 = 0; kt0 < 2048; kt0 += 64) {
    __syncthreads();
    *(bf16x8*)&Ks[r][c]     = kr0;
    *(bf16x8*)&Ks[r][c + 8] = kr1;
    if (PRET) {
      *(bf16x8*)&Vs[r][c]     = vr0;
      *(bf16x8*)&Vs[r][c + 8] = vr1;
    } else {
      union { bf16x8 v; ushort_t u[8]; } a0, a1;
      a0.v = vr0; a1.v = vr1;
      for (int i = 0; i < 8; i++) Vs[c + i][r] = a0.u[i];
      for (int i = 0; i < 8; i++) Vs[c + 8 + i][r] = a1.u[i];
    }
    commit8(&QsM[r][c],     pm0, mbf);
    commit8(&QsM[r][c + 8], pm1, mbf);
    __syncthreads();

    const int ktn = (kt0 + 64) & 2047;
    kr0 = *(const bf16x8*)&Kh[(size_t)(ktn + r) * 64 + c];
    kr1 = *(const bf16x8*)&Kh[(size_t)(ktn + r) * 64 + c + 8];
    if (PRET) {
      vr0 = *(const bf16x8*)&Vh[(size_t)r * 2048 + ktn + c];
      vr1 = *(const bf16x8*)&Vh[(size_t)r * 2048 + ktn + c + 8];
    } else {
      vr0 = *(const bf16x8*)&Vh[(size_t)(ktn + r) * 64 + c];
      vr1 = *(const bf16x8*)&Vh[(size_t)(ktn + r) * 64 + c + 8];
    }
    pm0 = pref8(mask, mstage + ktn, mbf);
    pm1 = pref8(mask, mstage + ktn + 8, mbf);

    f32x4 sc[4] = {};
#pragma unroll
    for (int j = 0; j < 4; j++) {
      bf16x8 bk0 = *(const bf16x8*)&Ks[j * 16 + l16][g * 8];
      bf16x8 bk1 = *(const bf16x8*)&Ks[j * 16 + l16][32 + g * 8];
      sc[j] = __builtin_amdgcn_mfma_f32_16x16x32_bf16(aq0, bk0, sc[j], 0, 0, 0);
      sc[j] = __builtin_amdgcn_mfma_f32_16x16x32_bf16(aq1, bk1, sc[j], 0, 0, 0);
    }

#pragma unroll
    for (int j = 0; j < 4; j++)
#pragma unroll
      for (int rr = 0; rr < 4; rr++) {
        float m = bf2f(QsM[mrow + rr][j * 16 + l16]);
        float s = fminf(sc[j][rr] * m, 80.f);
        float p = __expf(s);
        unsigned int pb = __float_as_uint(p);
        lpart[rr] += __uint_as_float(pb & 0xffff0000u);
        Ps[wave][g * 4 + rr][j * 16 + l16] = (ushort_t)(pb >> 16);
      }
    asm volatile("" ::: "memory");

    bf16x8 pf0 = *(const bf16x8*)&Ps[wave][l16][g * 8];
    bf16x8 pf1 = *(const bf16x8*)&Ps[wave][l16][32 + g * 8];
#pragma unroll
    for (int jd = 0; jd < 4; jd++) {
      bf16x8 vf0 = *(const bf16x8*)&Vs[jd * 16 + l16][g * 8];
      bf16x8 vf1 = *(const bf16x8*)&Vs[jd * 16 + l16][32 + g * 8];
      o_acc[jd] = __builtin_amdgcn_mfma_f32_16x16x32_bf16(pf0, vf0, o_acc[jd], 0, 0, 0);
      o_acc[jd] = __builtin_amdgcn_mfma_f32_16x16x32_bf16(pf1, vf1, o_acc[jd], 0, 0, 0);
    }
  }

  float rl[4];
  for (int rr = 0; rr < 4; rr++) {
    float l = lpart[rr];
    l += __shfl_xor(l, 1, 64);
    l += __shfl_xor(l, 2, 64);
    l += __shfl_xor(l, 4, 64);
    l += __shfl_xor(l, 8, 64);
    rl[rr] = 1.0f / l;
  }
  for (int jd = 0; jd < 4; jd++)
    for (int rr = 0; rr < 4; rr++) {
      int qrow = q0 + mrow + rr;
      ctx[((size_t)b * 2048 + qrow) * 1024 + h * 64 + jd * 16 + l16] =
          f2bf(o_acc[jd][rr] * rl[rr]);
    }
}

// ---------------------------------------------------------------------------
extern "C" void kernel_launch(void* const* d_in, const int* in_sizes, int n_in,
                              void* d_out, int out_size, void* d_ws, size_t ws_size,
                              hipStream_t stream) {
  (void)in_sizes; (void)n_in; (void)out_size;
  const void* key   = d_in[0];
  const void* value = d_in[1];
  const void* query = d_in[2];
  const void* mask  = d_in[3];
  // d_in[4] = i (unused)
  const void* Wq = d_in[5];
  const void* bq = d_in[6];
  const void* Wk = d_in[7];
  const void* bk = d_in[8];
  const void* Wv = d_in[9];
  const void* bv = d_in[10];
  const void* Wo = d_in[11];
  const void* bo = d_in[12];

  const size_t E = (size_t)2 * 2048 * 1024;
  ushort_t* Qw  = (ushort_t*)d_ws;           // bf16 [B,NH,S,PH]
  ushort_t* Kw  = Qw + E;
  ushort_t* Vw  = Kw + E;
  ushort_t* CTX = Vw + E;                    // bf16 [B,S,H]
  int* flag = (int*)(CTX + E);
  ushort_t* Vt   = (ushort_t*)((char*)flag + 256);   // bf16 [B,NH,PH,S]
  ushort_t* conv = Vt + E;                           // bf16 [4W][3X][Mt]
  ushort_t* Mt = conv + 4 * NW_ + 3 * NX_;
  float* Opart = (float*)(Mt + NM_);                 // 2 x [B,S,H] fp32 (z*E)
  float* Lpart = Opart + 2 * E;                      // 2 x [BH, S] fp32

  const size_t need_pret  = 4 * E * 2 + 256 + E * 2;
  const size_t need_W     = need_pret + 4 * NW_ * 2;
  const size_t need_WX    = need_W + 3 * NX_ * 2;
  const size_t need_all   = need_WX + NM_ * 2;
  const size_t need_split = need_all + 2 * E * 4 + 2 * (size_t)32 * 2048 * 4;
  const int pret  = ws_size >= need_pret ? 1 : 0;
  const int convW = (pret && ws_size >= need_W)   ? 1 : 0;
  const int convX = (pret && ws_size >= need_WX)  ? 1 : 0;
  const int convM = (pret && ws_size >= need_all) ? 1 : 0;
  const int ksplit = (convM && ws_size >= need_split) ? 1 : 0;

  detect_dtype_kernel<<<1, 64, 0, stream>>>((const ushort_t*)Wq, flag);

  if (convW) {
    int nseg = convM ? 8 : (convX ? 7 : 4);
    int nx   = (convX || convM) ? 2048 : 512;
    prep_kernel<<<dim3(nx, 1, nseg), 256, 0, stream>>>(
        query, key, value, Wq, Wk, Wv, Wo, mask, conv, Mt, flag);
  }
  const ushort_t* Wq_c = conv;
  const ushort_t* Wk_c = conv + NW_;
  const ushort_t* Wv_c = conv + 2 * NW_;
  const ushort_t* Wo_c = conv + 3 * NW_;
  const ushort_t* Xq_c = conv + 4 * NW_;
  const ushort_t* Xk_c = conv + 4 * NW_ + NX_;
  const ushort_t* Xv_c = conv + 4 * NW_ + 2 * NX_;

  if (convW && convX) {
    gemm_fast_kernel<1, 128><<<dim3(8, 32, 3), 256, 0, stream>>>(
        Xq_c, Xk_c, Xv_c, Wq_c, Wk_c, Wv_c, bq, bk, bv,
        Qw, Kw, Vw, flag);
  } else {
    proj_qkv_fb_kernel<<<dim3(8, 32, 3), 256, 0, stream>>>(
        query, key, value, Wq, bq, Wk, bk, Wv, bv, Qw, Kw, Vw, flag);
  }

  if (pret) {
    transpose_v_kernel<<<dim3(32, 32), 256, 0, stream>>>(Vw, Vt);
    if (convM && ksplit) {
      flash_attn128_kernel<1><<<dim3(32, 16, 2), 256, 0, stream>>>(
          Qw, Kw, Vt, Mt, CTX, Opart, Lpart);
      // R9 bug fixed: O partials live at Opart + 0 and Opart + E.
      combine_kernel<<<dim3(4096), 256, 0, stream>>>(
          Opart, Opart + E, Lpart, Lpart + (size_t)32 * 2048, CTX);
    } else if (convM) {
      flash_attn128_kernel<0><<<dim3(32, 16, 1), 256, 0, stream>>>(
          Qw, Kw, Vt, Mt, CTX, Opart, Lpart);
    } else {
      flash_attn_kernel<1><<<dim3(32, 32), 256, 0, stream>>>(Qw, Kw, Vt, mask, CTX, flag);
    }
  } else {
    flash_attn_kernel<0><<<dim3(32, 32), 256, 0, stream>>>(Qw, Kw, Vw, mask, CTX, flag);
  }

  if (convW) {
    gemm_fast_kernel<0, 64><<<dim3(16, 32, 1), 256, 0, stream>>>(
        CTX, CTX, CTX, Wo_c, Wo_c, Wo_c, bo, bo, bo,
        d_out, d_out, d_out, flag);
  } else {
    out_proj_fb_kernel<<<dim3(8, 32), 256, 0, stream>>>(CTX, Wo, bo, d_out, flag);
  }
}

// Round 11
// 326.960 us; speedup vs baseline: 1.0102x; 1.0102x over previous
//
#include <hip/hip_runtime.h>

typedef unsigned short ushort_t;
typedef __attribute__((ext_vector_type(8))) __bf16 bf16x8;
typedef __attribute__((ext_vector_type(4))) __bf16 bf16x4;
typedef __attribute__((ext_vector_type(4))) float f32x4;

__device__ inline float bf2f(ushort_t u) {
  union { unsigned int i; float f; } v; v.i = ((unsigned int)u) << 16; return v.f;
}
__device__ inline ushort_t f2bf(float f) {
  union { float f; unsigned int i; } v; v.f = f;
  unsigned int r = (v.i + 0x7fffu + ((v.i >> 16) & 1u)) >> 16;
  return (ushort_t)r;
}

// ---------------------------------------------------------------------------
// Dtype self-detection (flag=1: bf16 inputs, 0: fp32 inputs). Wave-parallel.
// ---------------------------------------------------------------------------
__global__ void detect_dtype_kernel(const ushort_t* __restrict__ w,
                                    int* __restrict__ flag) {
  int lane = threadIdx.x & 63;
  int cnt = 0;
  for (int i = 0; i < 4; i++) {
    float a = fabsf(bf2f(w[lane * 4 + i]));
    if (a >= 1e-4f && a <= 0.5f) cnt++;
  }
  for (int off = 1; off < 64; off <<= 1) cnt += __shfl_xor(cnt, off, 64);
  if (threadIdx.x == 0) *flag = (cnt >= 192) ? 1 : 0;
}

__device__ inline float ld1(const void* src, size_t idx, int isbf) {
  return isbf ? bf2f(((const ushort_t*)src)[idx]) : ((const float*)src)[idx];
}

// Register prefetch container (R5 lesson: named values only, never arrays
// passed by pointer — those go to scratch = HBM writes).
struct pre8 { float4 a, b; };
__device__ inline pre8 pref8(const void* src, size_t idx, int isbf) {
  pre8 u;
  if (isbf) {
    u.a = *(const float4*)((const ushort_t*)src + idx);
    u.b = u.a;
  } else {
    const float* s = (const float*)src + idx;
    u.a = *(const float4*)s;
    u.b = *(const float4*)(s + 4);
  }
  return u;
}
__device__ inline void commit8(ushort_t* dst, pre8 u, int isbf) {
  if (isbf) {
    *(float4*)dst = u.a;
  } else {
    union { bf16x8 v; ushort_t u8[8]; } t;
    t.u8[0] = f2bf(u.a.x); t.u8[1] = f2bf(u.a.y); t.u8[2] = f2bf(u.a.z); t.u8[3] = f2bf(u.a.w);
    t.u8[4] = f2bf(u.b.x); t.u8[5] = f2bf(u.b.y); t.u8[6] = f2bf(u.b.z); t.u8[7] = f2bf(u.b.w);
    *(bf16x8*)dst = t.v;
  }
}
__device__ inline void cvt8(ushort_t* dst, const void* src, size_t idx, int isbf) {
  commit8(dst, pref8(src, idx, isbf), isbf);
}

// ---------------------------------------------------------------------------
// PREP: bf16 conversion of W (segs 0-3) + X (segs 4-6), and mask transpose
// Mt[b][k][q] (seg 7) — merged into one launch. Coalesced b128 on both
// global sides of the transpose (R3 lesson: never 2B line-stride HBM stores).
// ---------------------------------------------------------------------------
#define NW_ ((size_t)1024 * 1024)
#define NX_ ((size_t)4096 * 1024)
#define NM_ ((size_t)2 * 2048 * 2048)

__global__ __launch_bounds__(256) void prep_kernel(
    const void* xq, const void* xk, const void* xv,
    const void* wq, const void* wk, const void* wv, const void* wo,
    const void* mask, ushort_t* __restrict__ dst, ushort_t* __restrict__ Mt,
    const int* __restrict__ flag) {
  __shared__ ushort_t T[64][72];
  const int seg = blockIdx.z;
  const int f = *flag;
  if (seg < 7) {
    const void* src; size_t n, doff;
    switch (seg) {
      case 0: src = wq; n = NW_; doff = 0;                 break;
      case 1: src = wk; n = NW_; doff = NW_;               break;
      case 2: src = wv; n = NW_; doff = 2 * NW_;           break;
      case 3: src = wo; n = NW_; doff = 3 * NW_;           break;
      case 4: src = xq; n = NX_; doff = 4 * NW_;           break;
      case 5: src = xk; n = NX_; doff = 4 * NW_ + NX_;     break;
      default: src = xv; n = NX_; doff = 4 * NW_ + 2 * NX_; break;
    }
    size_t i = ((size_t)blockIdx.x * 256 + threadIdx.x) * 8;
    if (i >= n) return;
    cvt8(&dst[doff + i], src, i, f);
  } else {
    // mask transpose: x in [0,2048): b = x>>10; q0/k0 64-tiles
    const int x = blockIdx.x;
    const int b = x >> 10, rem = x & 1023;
    const int q0 = (rem & 31) * 64, k0 = (rem >> 5) * 64;
    const int tid = threadIdx.x;
    const int r = tid >> 2, c = (tid & 3) * 16;
    const size_t src = (size_t)b * 2048 * 2048 + (size_t)(q0 + r) * 2048 + k0 + c;
    cvt8(&T[r][c],     mask, src, f);
    cvt8(&T[r][c + 8], mask, src + 8, f);
    __syncthreads();
    union { bf16x8 v; ushort_t u[8]; } o0, o1;
    for (int i = 0; i < 8; i++) o0.u[i] = T[c + i][r];
    for (int i = 0; i < 8; i++) o1.u[i] = T[c + 8 + i][r];
    ushort_t* d = Mt + (size_t)b * 2048 * 2048;
    *(bf16x8*)&d[(size_t)(k0 + r) * 2048 + q0 + c]     = o0.v;
    *(bf16x8*)&d[(size_t)(k0 + r) * 2048 + q0 + c + 8] = o1.v;
  }
}

// ---------------------------------------------------------------------------
// FAST GEMM (m97-style, validated R7): bf16 operands, global_load_lds,
// XOR-swizzled LDS. M-tile 128, N-tile NT (128 or 64), BK=64.
// NT=64 doubles block count for latency-exposed shapes (out_proj: 1->2
// blocks/CU). (R3 lesson: epilogue MODE compile-time.)
// ---------------------------------------------------------------------------
#define KDIM 1024
#define NDIM 1024

__device__ __forceinline__ void gld_lds16(ushort_t* lds, const ushort_t* g) {
  __builtin_amdgcn_global_load_lds(
      (const __attribute__((address_space(1))) void*)g,
      (__attribute__((address_space(3))) void*)lds, 16, 0, 0);
}

template <int MODE, int NT>
__global__ __launch_bounds__(256) void gemm_fast_kernel(
    const ushort_t* __restrict__ X0, const ushort_t* __restrict__ X1,
    const ushort_t* __restrict__ X2,
    const ushort_t* __restrict__ W0, const ushort_t* __restrict__ W1,
    const ushort_t* __restrict__ W2,
    const void* __restrict__ B0, const void* __restrict__ B1,
    const void* __restrict__ B2,
    void* __restrict__ O0, void* __restrict__ O1, void* __restrict__ O2,
    const int* __restrict__ flag) {
  constexpr int NJ = NT / 32;           // j-frags per wave (4 or 2)
  __shared__ ushort_t As[128 * 64];
  __shared__ ushort_t Bs[NT * 64];
  const int z = blockIdx.z;
  const ushort_t* X = z == 0 ? X0 : z == 1 ? X1 : X2;
  const ushort_t* W = z == 0 ? W0 : z == 1 ? W1 : W2;
  const void* Bias  = z == 0 ? B0 : z == 1 ? B1 : B2;
  void* Out         = z == 0 ? O0 : z == 1 ? O1 : O2;
  const int f = *flag;

  const int tid = threadIdx.x;
  const int wave = tid >> 6, lane = tid & 63;
  const int g = lane >> 4, l16 = lane & 15;
  const int m0 = blockIdx.y * 128, n0 = blockIdx.x * NT;
  const int wm = (wave >> 1) * 64, wn = (wave & 1) * (NT / 2);
  const int lr = lane >> 3;
  const int lc = (lane & 7) ^ lr;

  f32x4 acc[4][NJ] = {};

  for (int k0 = 0; k0 < KDIM; k0 += 64) {
#pragma unroll
    for (int q = 0; q < 4; q++) {
      const int row = wave * 32 + q * 8;
      gld_lds16(&As[row * 64], &X[(size_t)(m0 + row + lr) * KDIM + k0 + lc * 8]);
    }
#pragma unroll
    for (int q = 0; q < NT / 32; q++) {
      const int row = wave * (NT / 4) + q * 8;
      gld_lds16(&Bs[row * 64], &W[(size_t)(n0 + row + lr) * KDIM + k0 + lc * 8]);
    }
    __syncthreads();

    bf16x8 af[2][4], bfr[2][NJ];
#pragma unroll
    for (int kk = 0; kk < 2; kk++) {
      const int cs = ((g + 4 * kk) ^ (l16 & 7)) * 8;
#pragma unroll
      for (int i = 0; i < 4; i++)
        af[kk][i]  = *(const bf16x8*)&As[(wm + i * 16 + l16) * 64 + cs];
#pragma unroll
      for (int j = 0; j < NJ; j++)
        bfr[kk][j] = *(const bf16x8*)&Bs[(wn + j * 16 + l16) * 64 + cs];
    }
#pragma unroll
    for (int kk = 0; kk < 2; kk++)
#pragma unroll
      for (int i = 0; i < 4; i++)
#pragma unroll
        for (int j = 0; j < NJ; j++)
          acc[i][j] = __builtin_amdgcn_mfma_f32_16x16x32_bf16(
              af[kk][i], bfr[kk][j], acc[i][j], 0, 0, 0);
    __syncthreads();
  }

  for (int i = 0; i < 4; i++)
    for (int j = 0; j < NJ; j++)
      for (int r = 0; r < 4; r++) {
        int m = m0 + wm + i * 16 + g * 4 + r;   // C/D: row=(lane>>4)*4+reg
        int n = n0 + wn + j * 16 + l16;         //      col=lane&15
        float v = acc[i][j][r] + ld1(Bias, n, f);
        if (MODE == 0) {
          if (f) ((ushort_t*)Out)[(size_t)m * NDIM + n] = f2bf(v);
          else   ((float*)Out)[(size_t)m * NDIM + n] = v;
        } else {
          int b = m >> 11, s = m & 2047, h = n >> 6, d = n & 63;
          ((ushort_t*)Out)[((((size_t)b * 16 + h) * 2048) + s) * 64 + d] = f2bf(v);
        }
      }
}

// ---------------------------------------------------------------------------
// FALLBACK GEMM (any dtype): VGPR-roundtrip staging, BK=32.
// ---------------------------------------------------------------------------
#define BK 32

template <int MODE>
__device__ inline void gemm_body(const void* __restrict__ X,
                                 const void* __restrict__ W,
                                 const void* __restrict__ Bias,
                                 void* __restrict__ Out,
                                 int xbf, int wbf, int bbf, int obf) {
  __shared__ ushort_t As[128][BK + 8];
  __shared__ ushort_t Bs[128][BK + 8];
  const int tid = threadIdx.x;
  const int wave = tid >> 6, lane = tid & 63;
  const int g = lane >> 4, l16 = lane & 15;
  const int m0 = blockIdx.y * 128, n0 = blockIdx.x * 128;
  const int wm = (wave >> 1) * 64, wn = (wave & 1) * 64;

  f32x4 acc[4][4] = {};
  const int r0 = tid >> 2, c0 = (tid & 3) * 8;
  const size_t ia0 = (size_t)(m0 + r0) * KDIM + c0;
  const size_t ia1 = (size_t)(m0 + r0 + 64) * KDIM + c0;
  const size_t ib0 = (size_t)(n0 + r0) * KDIM + c0;
  const size_t ib1 = (size_t)(n0 + r0 + 64) * KDIM + c0;

  pre8 pa0 = pref8(X, ia0, xbf), pa1 = pref8(X, ia1, xbf);
  pre8 pb0 = pref8(W, ib0, wbf), pb1 = pref8(W, ib1, wbf);

  for (int k0 = 0; k0 < KDIM; k0 += BK) {
    commit8(&As[r0][c0],      pa0, xbf);
    commit8(&As[r0 + 64][c0], pa1, xbf);
    commit8(&Bs[r0][c0],      pb0, wbf);
    commit8(&Bs[r0 + 64][c0], pb1, wbf);
    const int kn = (k0 + BK) & (KDIM - 1);
    pa0 = pref8(X, ia0 + kn, xbf); pa1 = pref8(X, ia1 + kn, xbf);
    pb0 = pref8(W, ib0 + kn, wbf); pb1 = pref8(W, ib1 + kn, wbf);
    __syncthreads();
    bf16x8 af[4], bfr[4];
    for (int i = 0; i < 4; i++) af[i]  = *(const bf16x8*)&As[wm + i * 16 + l16][g * 8];
    for (int j = 0; j < 4; j++) bfr[j] = *(const bf16x8*)&Bs[wn + j * 16 + l16][g * 8];
    for (int i = 0; i < 4; i++)
      for (int j = 0; j < 4; j++)
        acc[i][j] = __builtin_amdgcn_mfma_f32_16x16x32_bf16(af[i], bfr[j], acc[i][j], 0, 0, 0);
    __syncthreads();
  }
  for (int i = 0; i < 4; i++)
    for (int j = 0; j < 4; j++)
      for (int r = 0; r < 4; r++) {
        int m = m0 + wm + i * 16 + g * 4 + r;
        int n = n0 + wn + j * 16 + l16;
        float v = acc[i][j][r] + ld1(Bias, n, bbf);
        if (MODE == 0) {
          if (obf) ((ushort_t*)Out)[(size_t)m * NDIM + n] = f2bf(v);
          else     ((float*)Out)[(size_t)m * NDIM + n] = v;
        } else {
          int b = m >> 11, s = m & 2047, h = n >> 6, d = n & 63;
          ((ushort_t*)Out)[((((size_t)b * 16 + h) * 2048) + s) * 64 + d] = f2bf(v);
        }
      }
}

__global__ __launch_bounds__(256) void proj_qkv_fb_kernel(
    const void* __restrict__ query, const void* __restrict__ key,
    const void* __restrict__ value,
    const void* __restrict__ Wq, const void* __restrict__ bq,
    const void* __restrict__ Wk, const void* __restrict__ bk,
    const void* __restrict__ Wv, const void* __restrict__ bv,
    ushort_t* __restrict__ Q, ushort_t* __restrict__ K, ushort_t* __restrict__ V,
    const int* __restrict__ flag) {
  int f = *flag;
  int z = blockIdx.z;
  const void* X = z == 0 ? query : z == 1 ? key : value;
  const void* W = z == 0 ? Wq : z == 1 ? Wk : Wv;
  const void* B = z == 0 ? bq : z == 1 ? bk : bv;
  ushort_t* O  = z == 0 ? Q  : z == 1 ? K  : V;
  gemm_body<1>(X, W, B, O, f, f, f, 1);
}

__global__ __launch_bounds__(256) void out_proj_fb_kernel(
    const ushort_t* __restrict__ X, const void* __restrict__ W,
    const void* __restrict__ B, void* __restrict__ O,
    const int* __restrict__ flag) {
  int f = *flag;
  gemm_body<0>(X, W, B, O, 1, f, f, f);
}

// ---------------------------------------------------------------------------
// V transpose: Vt[bh][d][s] = V[bh][s][d]. Validated R5.
// ---------------------------------------------------------------------------
__global__ __launch_bounds__(256) void transpose_v_kernel(
    const ushort_t* __restrict__ Vin, ushort_t* __restrict__ Vout) {
  __shared__ ushort_t T[64][72];
  const int tid = threadIdx.x;
  const int r = tid >> 2, c = (tid & 3) * 16;
  const int bh = blockIdx.y;
  const int s0 = blockIdx.x * 64;
  const ushort_t* src = Vin + (size_t)bh * 2048 * 64;
  *(bf16x8*)&T[r][c]     = *(const bf16x8*)&src[(size_t)(s0 + r) * 64 + c];
  *(bf16x8*)&T[r][c + 8] = *(const bf16x8*)&src[(size_t)(s0 + r) * 64 + c + 8];
  __syncthreads();
  union { bf16x8 v; ushort_t u[8]; } o0, o1;
  for (int i = 0; i < 8; i++) o0.u[i] = T[c + i][r];
  for (int i = 0; i < 8; i++) o1.u[i] = T[c + 8 + i][r];
  ushort_t* dst = Vout + (size_t)bh * 64 * 2048;
  *(bf16x8*)&dst[(size_t)r * 2048 + s0 + c]     = o0.v;
  *(bf16x8*)&dst[(size_t)r * 2048 + s0 + c + 8] = o1.v;
}

// ---------------------------------------------------------------------------
// Flash attention v9 (q-tile 128, K-split). R11 change: Ps row stride
// 72 -> 66 elements (132 B = 33 dwords, odd -> reads land bank l16,
// <=2-way). LDS 53760 -> 52224 B (<= 52 KB): if LDS allocates in 4 KB
// granules this is what actually enables 3 blocks/CU (R10's 53760 rounds
// to 56 KB -> 3x56 > 160 KB -> stuck at 2 blocks, Occupancy ~18%).
// SPLIT=1: z in {0,1} does K half, writes unnormalized fp32 O partials
// (Opart + z*E) + l sums; exact merge (no online max): (o1+o2)/(l1+l2).
// ---------------------------------------------------------------------------
#define PSS 66

template <int SPLIT>
__global__ __launch_bounds__(256, 3) void flash_attn128_kernel(
    const ushort_t* __restrict__ Q, const ushort_t* __restrict__ K,
    const ushort_t* __restrict__ Vt, const ushort_t* __restrict__ Mt,
    ushort_t* __restrict__ ctx, float* __restrict__ Opart,
    float* __restrict__ Lpart) {
  __shared__ ushort_t Ks[64 * 72];
  __shared__ ushort_t Vs[64 * 72];
  __shared__ ushort_t MQ[8448];         // Q staging 128x66, then mask 64x132
  __shared__ ushort_t Ps[4][32 * PSS];  // per-wave P tile [32q][64k]

  const int tid = threadIdx.x;
  const int wave = tid >> 6, lane = tid & 63;
  const int g = lane >> 4, l16 = lane & 15;
  const int bh = blockIdx.x;
  const int b = bh >> 4, h = bh & 15;
  const int q0 = blockIdx.y * 128;
  const int z = SPLIT ? blockIdx.z : 0;
  const int kbase = z * 1024, kend = SPLIT ? kbase + 1024 : 2048;

  const ushort_t* Qh = Q + (size_t)bh * 2048 * 64;
  const ushort_t* Kh = K + (size_t)bh * 2048 * 64;
  const ushort_t* Vh = Vt + (size_t)bh * 64 * 2048;            // [d][s]
  const ushort_t* Mh = Mt + (size_t)b * 2048 * 2048 + q0;      // [k][q0..]

  // ---- Q stage (128x64 into MQ stride 66) with exact 1/8 prescale ----
  {
    const int qr = tid >> 1, qc = (tid & 1) * 32;
#pragma unroll
    for (int ch = 0; ch < 4; ch++) {
      union { bf16x8 v; ushort_t u[8]; } a;
      a.v = *(const bf16x8*)&Qh[(size_t)(q0 + qr) * 64 + qc + ch * 8];
      for (int i = 0; i < 8; i++) a.u[i] = f2bf(bf2f(a.u[i]) * 0.125f);
      *(bf16x8*)&MQ[qr * 66 + qc + ch * 8] = a.v;
    }
  }
  __syncthreads();
  bf16x8 aq[2][2];
#pragma unroll
  for (int t = 0; t < 2; t++)
#pragma unroll
    for (int kk = 0; kk < 2; kk++)
      aq[t][kk] = *(const bf16x8*)&MQ[(wave * 32 + t * 16 + l16) * 66 + kk * 32 + g * 8];
  // iter-0 barrier A orders these reads before any wave's mask writes to MQ.

  float lpart[2][4] = {};
  f32x4 o_acc[2][4] = {};

  const int r = tid >> 2, c = (tid & 3) * 16;     // K/V staging coords
  const int mc = (tid & 3) * 32;                  // mask staging col base

  // ---- prologue prefetch (named regs only — R5 lesson) ----
  bf16x8 kr0 = *(const bf16x8*)&Kh[(size_t)(kbase + r) * 64 + c];
  bf16x8 kr1 = *(const bf16x8*)&Kh[(size_t)(kbase + r) * 64 + c + 8];
  bf16x8 vr0 = *(const bf16x8*)&Vh[(size_t)r * 2048 + kbase + c];
  bf16x8 vr1 = *(const bf16x8*)&Vh[(size_t)r * 2048 + kbase + c + 8];
  bf16x8 pm0 = *(const bf16x8*)&Mh[(size_t)(kbase + r) * 2048 + mc];
  bf16x8 pm1 = *(const bf16x8*)&Mh[(size_t)(kbase + r) * 2048 + mc + 8];
  bf16x8 pm2 = *(const bf16x8*)&Mh[(size_t)(kbase + r) * 2048 + mc + 16];
  bf16x8 pm3 = *(const bf16x8*)&Mh[(size_t)(kbase + r) * 2048 + mc + 24];

  for (int kt0 = kbase; kt0 < kend; kt0 += 64) {
    __syncthreads();   // A: all waves done with prev Ks/Vs/MQ/Ps reads
    *(bf16x8*)&Ks[r * 72 + c]      = kr0;
    *(bf16x8*)&Ks[r * 72 + c + 8]  = kr1;
    *(bf16x8*)&Vs[r * 72 + c]      = vr0;
    *(bf16x8*)&Vs[r * 72 + c + 8]  = vr1;
    *(bf16x8*)&MQ[r * 132 + mc]      = pm0;
    *(bf16x8*)&MQ[r * 132 + mc + 8]  = pm1;
    *(bf16x8*)&MQ[r * 132 + mc + 16] = pm2;
    *(bf16x8*)&MQ[r * 132 + mc + 24] = pm3;
    __syncthreads();   // B: staging visible

    // ---- issue next-tile loads; drained at next barrier A ----
    const int ktn = (kt0 + 64) & 2047;            // wrap: last pref harmless
    kr0 = *(const bf16x8*)&Kh[(size_t)(ktn + r) * 64 + c];
    kr1 = *(const bf16x8*)&Kh[(size_t)(ktn + r) * 64 + c + 8];
    vr0 = *(const bf16x8*)&Vh[(size_t)r * 2048 + ktn + c];
    vr1 = *(const bf16x8*)&Vh[(size_t)r * 2048 + ktn + c + 8];
    pm0 = *(const bf16x8*)&Mh[(size_t)(ktn + r) * 2048 + mc];
    pm1 = *(const bf16x8*)&Mh[(size_t)(ktn + r) * 2048 + mc + 8];
    pm2 = *(const bf16x8*)&Mh[(size_t)(ktn + r) * 2048 + mc + 16];
    pm3 = *(const bf16x8*)&Mh[(size_t)(ktn + r) * 2048 + mc + 24];

    // ---- scores: 32 q-rows x 64 k-cols per wave ----
    f32x4 sc[2][4] = {};
#pragma unroll
    for (int j = 0; j < 4; j++) {
      bf16x8 bk0 = *(const bf16x8*)&Ks[(j * 16 + l16) * 72 + g * 8];
      bf16x8 bk1 = *(const bf16x8*)&Ks[(j * 16 + l16) * 72 + 32 + g * 8];
#pragma unroll
      for (int t = 0; t < 2; t++) {
        sc[t][j] = __builtin_amdgcn_mfma_f32_16x16x32_bf16(aq[t][0], bk0, sc[t][j], 0, 0, 0);
        sc[t][j] = __builtin_amdgcn_mfma_f32_16x16x32_bf16(aq[t][1], bk1, sc[t][j], 0, 0, 0);
      }
    }

    // ---- p = exp(s*m); mask via ds_read_b64 (4 contiguous q); bf16 P ----
#pragma unroll
    for (int t = 0; t < 2; t++)
#pragma unroll
      for (int j = 0; j < 4; j++) {
        union { bf16x4 v; ushort_t u[4]; } m4;
        m4.v = *(const bf16x4*)&MQ[(j * 16 + l16) * 132 + wave * 32 + t * 16 + g * 4];
#pragma unroll
        for (int rr = 0; rr < 4; rr++) {
          float s = fminf(sc[t][j][rr] * bf2f(m4.u[rr]), 80.f);
          float p = __expf(s);
          unsigned int pb = __float_as_uint(p);
          lpart[t][rr] += __uint_as_float(pb & 0xffff0000u);
          Ps[wave][(t * 16 + g * 4 + rr) * PSS + j * 16 + l16] = (ushort_t)(pb >> 16);
        }
      }
    asm volatile("" ::: "memory");   // keep ds_reads below after ds_writes

    // ---- PV: o_acc[t][jd] += P[t] x V ----
    bf16x8 pf00 = *(const bf16x8*)&Ps[wave][(l16) * PSS + g * 8];
    bf16x8 pf01 = *(const bf16x8*)&Ps[wave][(l16) * PSS + 32 + g * 8];
    bf16x8 pf10 = *(const bf16x8*)&Ps[wave][(16 + l16) * PSS + g * 8];
    bf16x8 pf11 = *(const bf16x8*)&Ps[wave][(16 + l16) * PSS + 32 + g * 8];
#pragma unroll
    for (int jd = 0; jd < 4; jd++) {
      bf16x8 vf0 = *(const bf16x8*)&Vs[(jd * 16 + l16) * 72 + g * 8];
      bf16x8 vf1 = *(const bf16x8*)&Vs[(jd * 16 + l16) * 72 + 32 + g * 8];
      o_acc[0][jd] = __builtin_amdgcn_mfma_f32_16x16x32_bf16(pf00, vf0, o_acc[0][jd], 0, 0, 0);
      o_acc[0][jd] = __builtin_amdgcn_mfma_f32_16x16x32_bf16(pf01, vf1, o_acc[0][jd], 0, 0, 0);
      o_acc[1][jd] = __builtin_amdgcn_mfma_f32_16x16x32_bf16(pf10, vf0, o_acc[1][jd], 0, 0, 0);
      o_acc[1][jd] = __builtin_amdgcn_mfma_f32_16x16x32_bf16(pf11, vf1, o_acc[1][jd], 0, 0, 0);
    }
  }

  // ---- epilogue ----
  if (SPLIT) {
    float* Ow = Opart + (size_t)z * ((size_t)2 * 2048 * 1024);
    float* Lw = Lpart + (size_t)z * (32 * 2048);
#pragma unroll
    for (int t = 0; t < 2; t++) {
      float ls[4];
#pragma unroll
      for (int rr = 0; rr < 4; rr++) {
        float l = lpart[t][rr];
        l += __shfl_xor(l, 1, 64);
        l += __shfl_xor(l, 2, 64);
        l += __shfl_xor(l, 4, 64);
        l += __shfl_xor(l, 8, 64);
        ls[rr] = l;
      }
      if (l16 == 0)
#pragma unroll
        for (int rr = 0; rr < 4; rr++)
          Lw[(size_t)bh * 2048 + q0 + wave * 32 + t * 16 + g * 4 + rr] = ls[rr];
#pragma unroll
      for (int jd = 0; jd < 4; jd++)
#pragma unroll
        for (int rr = 0; rr < 4; rr++) {
          int qrow = q0 + wave * 32 + t * 16 + g * 4 + rr;
          Ow[((size_t)b * 2048 + qrow) * 1024 + h * 64 + jd * 16 + l16] =
              o_acc[t][jd][rr];
        }
    }
  } else {
#pragma unroll
    for (int t = 0; t < 2; t++) {
      float rl[4];
#pragma unroll
      for (int rr = 0; rr < 4; rr++) {
        float l = lpart[t][rr];
        l += __shfl_xor(l, 1, 64);
        l += __shfl_xor(l, 2, 64);
        l += __shfl_xor(l, 4, 64);
        l += __shfl_xor(l, 8, 64);
        rl[rr] = 1.0f / l;
      }
#pragma unroll
      for (int jd = 0; jd < 4; jd++)
#pragma unroll
        for (int rr = 0; rr < 4; rr++) {
          int qrow = q0 + wave * 32 + t * 16 + g * 4 + rr;
          ctx[((size_t)b * 2048 + qrow) * 1024 + h * 64 + jd * 16 + l16] =
              f2bf(o_acc[t][jd][rr] * rl[rr]);
        }
    }
  }
}

// ---------------------------------------------------------------------------
// Combine: ctx = (O0 + O1) / (L0 + L1). Exact merge of the two K-halves.
// ---------------------------------------------------------------------------
__global__ __launch_bounds__(256) void combine_kernel(
    const float* __restrict__ O0, const float* __restrict__ O1,
    const float* __restrict__ L0, const float* __restrict__ L1,
    ushort_t* __restrict__ ctx) {
  size_t i = ((size_t)blockIdx.x * 256 + threadIdx.x) * 4;
  int h = (int)((i & 1023) >> 6);
  size_t s = (i >> 10) & 2047, b = i >> 21;
  size_t li = (b * 16 + h) * 2048 + s;
  float rl = 1.0f / (L0[li] + L1[li]);
  float4 a = *(const float4*)&O0[i];
  float4 c = *(const float4*)&O1[i];
  union { bf16x4 v; ushort_t u[4]; } o;
  o.u[0] = f2bf((a.x + c.x) * rl);
  o.u[1] = f2bf((a.y + c.y) * rl);
  o.u[2] = f2bf((a.z + c.z) * rl);
  o.u[3] = f2bf((a.w + c.w) * rl);
  *(bf16x4*)&ctx[i] = o.v;
}

// ---------------------------------------------------------------------------
// Fallback flash (R7, validated): q-tile 64, mask from global (any dtype).
// ---------------------------------------------------------------------------
#define FS 72

template <int PRET>
__global__ __launch_bounds__(256, 4) void flash_attn_kernel(
    const ushort_t* __restrict__ Q, const ushort_t* __restrict__ K,
    const ushort_t* __restrict__ V, const void* __restrict__ mask,
    ushort_t* __restrict__ ctx, const int* __restrict__ flag) {
  __shared__ ushort_t QsM[64][FS];
  __shared__ ushort_t Ks[64][FS];
  __shared__ ushort_t Vs[64][FS];
  __shared__ ushort_t Ps[4][16][FS];

  const int mbf = *flag;
  const int tid = threadIdx.x;
  const int wave = tid >> 6, lane = tid & 63;
  const int g = lane >> 4, l16 = lane & 15;
  const int bh = blockIdx.x;
  const int b = bh >> 4, h = bh & 15;
  const int q0 = blockIdx.y * 64;

  const ushort_t* Qh = Q + (size_t)bh * 2048 * 64;
  const ushort_t* Kh = K + (size_t)bh * 2048 * 64;
  const ushort_t* Vh = PRET ? V + (size_t)bh * 64 * 2048
                            : V + (size_t)bh * 2048 * 64;
  const int mrow = wave * 16 + g * 4;
  const int r = tid >> 2, c = (tid & 3) * 16;
  const size_t mstage = (size_t)b * 2048 * 2048 + (size_t)(q0 + r) * 2048 + c;

  {
    union { bf16x8 v; ushort_t u[8]; } a0, a1;
    a0.v = *(const bf16x8*)&Qh[(size_t)(q0 + r) * 64 + c];
    a1.v = *(const bf16x8*)&Qh[(size_t)(q0 + r) * 64 + c + 8];
    for (int i = 0; i < 8; i++) {
      a0.u[i] = f2bf(bf2f(a0.u[i]) * 0.125f);
      a1.u[i] = f2bf(bf2f(a1.u[i]) * 0.125f);
    }
    *(bf16x8*)&QsM[r][c]     = a0.v;
    *(bf16x8*)&QsM[r][c + 8] = a1.v;
  }
  __syncthreads();
  const bf16x8 aq0 = *(const bf16x8*)&QsM[wave * 16 + l16][g * 8];
  const bf16x8 aq1 = *(const bf16x8*)&QsM[wave * 16 + l16][32 + g * 8];

  float lpart[4] = {0.f, 0.f, 0.f, 0.f};
  f32x4 o_acc[4] = {};

  bf16x8 kr0 = *(const bf16x8*)&Kh[(size_t)r * 64 + c];
  bf16x8 kr1 = *(const bf16x8*)&Kh[(size_t)r * 64 + c + 8];
  bf16x8 vr0, vr1;
  if (PRET) {
    vr0 = *(const bf16x8*)&Vh[(size_t)r * 2048 + c];
    vr1 = *(const bf16x8*)&Vh[(size_t)r * 2048 + c + 8];
  } else {
    vr0 = *(const bf16x8*)&Vh[(size_t)r * 64 + c];
    vr1 = *(const bf16x8*)&Vh[(size_t)r * 64 + c + 8];
  }
  pre8 pm0 = pref8(mask, mstage, mbf);
  pre8 pm1 = pref8(mask, mstage + 8, mbf);

  for (int kt0 = 0; kt0 < 2048; kt0 += 64) {
    __syncthreads();
    *(bf16x8*)&Ks[r][c]     = kr0;
    *(bf16x8*)&Ks[r][c + 8] = kr1;
    if (PRET) {
      *(bf16x8*)&Vs[r][c]     = vr0;
      *(bf16x8*)&Vs[r][c + 8] = vr1;
    } else {
      union { bf16x8 v; ushort_t u[8]; } a0, a1;
      a0.v = vr0; a1.v = vr1;
      for (int i = 0; i < 8; i++) Vs[c + i][r] = a0.u[i];
      for (int i = 0; i < 8; i++) Vs[c + 8 + i][r] = a1.u[i];
    }
    commit8(&QsM[r][c],     pm0, mbf);
    commit8(&QsM[r][c + 8], pm1, mbf);
    __syncthreads();

    const int ktn = (kt0 + 64) & 2047;
    kr0 = *(const bf16x8*)&Kh[(size_t)(ktn + r) * 64 + c];
    kr1 = *(const bf16x8*)&Kh[(size_t)(ktn + r) * 64 + c + 8];
    if (PRET) {
      vr0 = *(const bf16x8*)&Vh[(size_t)r * 2048 + ktn + c];
      vr1 = *(const bf16x8*)&Vh[(size_t)r * 2048 + ktn + c + 8];
    } else {
      vr0 = *(const bf16x8*)&Vh[(size_t)(ktn + r) * 64 + c];
      vr1 = *(const bf16x8*)&Vh[(size_t)(ktn + r) * 64 + c + 8];
    }
    pm0 = pref8(mask, mstage + ktn, mbf);
    pm1 = pref8(mask, mstage + ktn + 8, mbf);

    f32x4 sc[4] = {};
#pragma unroll
    for (int j = 0; j < 4; j++) {
      bf16x8 bk0 = *(const bf16x8*)&Ks[j * 16 + l16][g * 8];
      bf16x8 bk1 = *(const bf16x8*)&Ks[j * 16 + l16][32 + g * 8];
      sc[j] = __builtin_amdgcn_mfma_f32_16x16x32_bf16(aq0, bk0, sc[j], 0, 0, 0);
      sc[j] = __builtin_amdgcn_mfma_f32_16x16x32_bf16(aq1, bk1, sc[j], 0, 0, 0);
    }

#pragma unroll
    for (int j = 0; j < 4; j++)
#pragma unroll
      for (int rr = 0; rr < 4; rr++) {
        float m = bf2f(QsM[mrow + rr][j * 16 + l16]);
        float s = fminf(sc[j][rr] * m, 80.f);
        float p = __expf(s);
        unsigned int pb = __float_as_uint(p);
        lpart[rr] += __uint_as_float(pb & 0xffff0000u);
        Ps[wave][g * 4 + rr][j * 16 + l16] = (ushort_t)(pb >> 16);
      }
    asm volatile("" ::: "memory");

    bf16x8 pf0 = *(const bf16x8*)&Ps[wave][l16][g * 8];
    bf16x8 pf1 = *(const bf16x8*)&Ps[wave][l16][32 + g * 8];
#pragma unroll
    for (int jd = 0; jd < 4; jd++) {
      bf16x8 vf0 = *(const bf16x8*)&Vs[jd * 16 + l16][g * 8];
      bf16x8 vf1 = *(const bf16x8*)&Vs[jd * 16 + l16][32 + g * 8];
      o_acc[jd] = __builtin_amdgcn_mfma_f32_16x16x32_bf16(pf0, vf0, o_acc[jd], 0, 0, 0);
      o_acc[jd] = __builtin_amdgcn_mfma_f32_16x16x32_bf16(pf1, vf1, o_acc[jd], 0, 0, 0);
    }
  }

  float rl[4];
  for (int rr = 0; rr < 4; rr++) {
    float l = lpart[rr];
    l += __shfl_xor(l, 1, 64);
    l += __shfl_xor(l, 2, 64);
    l += __shfl_xor(l, 4, 64);
    l += __shfl_xor(l, 8, 64);
    rl[rr] = 1.0f / l;
  }
  for (int jd = 0; jd < 4; jd++)
    for (int rr = 0; rr < 4; rr++) {
      int qrow = q0 + mrow + rr;
      ctx[((size_t)b * 2048 + qrow) * 1024 + h * 64 + jd * 16 + l16] =
          f2bf(o_acc[jd][rr] * rl[rr]);
    }
}

// ---------------------------------------------------------------------------
extern "C" void kernel_launch(void* const* d_in, const int* in_sizes, int n_in,
                              void* d_out, int out_size, void* d_ws, size_t ws_size,
                              hipStream_t stream) {
  (void)in_sizes; (void)n_in; (void)out_size;
  const void* key   = d_in[0];
  const void* value = d_in[1];
  const void* query = d_in[2];
  const void* mask  = d_in[3];
  // d_in[4] = i (unused)
  const void* Wq = d_in[5];
  const void* bq = d_in[6];
  const void* Wk = d_in[7];
  const void* bk = d_in[8];
  const void* Wv = d_in[9];
  const void* bv = d_in[10];
  const void* Wo = d_in[11];
  const void* bo = d_in[12];

  const size_t E = (size_t)2 * 2048 * 1024;
  ushort_t* Qw  = (ushort_t*)d_ws;           // bf16 [B,NH,S,PH]
  ushort_t* Kw  = Qw + E;
  ushort_t* Vw  = Kw + E;
  ushort_t* CTX = Vw + E;                    // bf16 [B,S,H]
  int* flag = (int*)(CTX + E);
  ushort_t* Vt   = (ushort_t*)((char*)flag + 256);   // bf16 [B,NH,PH,S]
  ushort_t* conv = Vt + E;                           // bf16 [4W][3X][Mt]
  ushort_t* Mt = conv + 4 * NW_ + 3 * NX_;
  float* Opart = (float*)(Mt + NM_);                 // 2 x [B,S,H] fp32 (z*E)
  float* Lpart = Opart + 2 * E;                      // 2 x [BH, S] fp32

  const size_t need_pret  = 4 * E * 2 + 256 + E * 2;
  const size_t need_W     = need_pret + 4 * NW_ * 2;
  const size_t need_WX    = need_W + 3 * NX_ * 2;
  const size_t need_all   = need_WX + NM_ * 2;
  const size_t need_split = need_all + 2 * E * 4 + 2 * (size_t)32 * 2048 * 4;
  const int pret  = ws_size >= need_pret ? 1 : 0;
  const int convW = (pret && ws_size >= need_W)   ? 1 : 0;
  const int convX = (pret && ws_size >= need_WX)  ? 1 : 0;
  const int convM = (pret && ws_size >= need_all) ? 1 : 0;
  const int ksplit = (convM && ws_size >= need_split) ? 1 : 0;

  detect_dtype_kernel<<<1, 64, 0, stream>>>((const ushort_t*)Wq, flag);

  if (convW) {
    int nseg = convM ? 8 : (convX ? 7 : 4);
    int nx   = (convX || convM) ? 2048 : 512;
    prep_kernel<<<dim3(nx, 1, nseg), 256, 0, stream>>>(
        query, key, value, Wq, Wk, Wv, Wo, mask, conv, Mt, flag);
  }
  const ushort_t* Wq_c = conv;
  const ushort_t* Wk_c = conv + NW_;
  const ushort_t* Wv_c = conv + 2 * NW_;
  const ushort_t* Wo_c = conv + 3 * NW_;
  const ushort_t* Xq_c = conv + 4 * NW_;
  const ushort_t* Xk_c = conv + 4 * NW_ + NX_;
  const ushort_t* Xv_c = conv + 4 * NW_ + 2 * NX_;

  if (convW && convX) {
    gemm_fast_kernel<1, 128><<<dim3(8, 32, 3), 256, 0, stream>>>(
        Xq_c, Xk_c, Xv_c, Wq_c, Wk_c, Wv_c, bq, bk, bv,
        Qw, Kw, Vw, flag);
  } else {
    proj_qkv_fb_kernel<<<dim3(8, 32, 3), 256, 0, stream>>>(
        query, key, value, Wq, bq, Wk, bk, Wv, bv, Qw, Kw, Vw, flag);
  }

  if (pret) {
    transpose_v_kernel<<<dim3(32, 32), 256, 0, stream>>>(Vw, Vt);
    if (convM && ksplit) {
      flash_attn128_kernel<1><<<dim3(32, 16, 2), 256, 0, stream>>>(
          Qw, Kw, Vt, Mt, CTX, Opart, Lpart);
      combine_kernel<<<dim3(4096), 256, 0, stream>>>(
          Opart, Opart + E, Lpart, Lpart + (size_t)32 * 2048, CTX);
    } else if (convM) {
      flash_attn128_kernel<0><<<dim3(32, 16, 1), 256, 0, stream>>>(
          Qw, Kw, Vt, Mt, CTX, Opart, Lpart);
    } else {
      flash_attn_kernel<1><<<dim3(32, 32), 256, 0, stream>>>(Qw, Kw, Vt, mask, CTX, flag);
    }
  } else {
    flash_attn_kernel<0><<<dim3(32, 32), 256, 0, stream>>>(Qw, Kw, Vw, mask, CTX, flag);
  }

  if (convW) {
    gemm_fast_kernel<0, 64><<<dim3(16, 32, 1), 256, 0, stream>>>(
        CTX, CTX, CTX, Wo_c, Wo_c, Wo_c, bo, bo, bo,
        d_out, d_out, d_out, flag);
  } else {
    out_proj_fb_kernel<<<dim3(8, 32), 256, 0, stream>>>(CTX, Wo, bo, d_out, flag);
  }
}